// Round 6
// baseline (81.995 us; speedup 1.0000x reference)
//
#include <hip/hip_runtime.h>

#define NB 16
#define S_TOK 577
#define SP 576
#define DIM 768
#define NC 256
#define NCLS 1000
#define TK 16
#define HCH 6
#define HCHS 96  // 576/6

typedef __attribute__((ext_vector_type(8))) __bf16 bf16x8;
typedef __attribute__((ext_vector_type(4))) float f32x4;

// ---------------- Kernel 0: split q (rows 1..576) and cw into bf16 hi/lo ----
// Also zeroes W. chunk = 8 consecutive elements.
__global__ __launch_bounds__(256) void cvt_split_k(const float* __restrict__ q,
                                                   const float* __restrict__ cw,
                                                   __bf16* __restrict__ qph,
                                                   __bf16* __restrict__ qpl,
                                                   __bf16* __restrict__ cwh,
                                                   __bf16* __restrict__ cwl,
                                                   float* __restrict__ W) {
  const int gid = blockIdx.x * 256 + threadIdx.x;
  if (gid < NB * SP) W[gid] = 0.f;
  const int QCH = NB * SP * (DIM / 8);  // 884736
  const float* src;
  __bf16 *dh, *dl;
  if (gid < QCH) {
    const int rid = gid / (DIM / 8);
    const int kc = gid % (DIM / 8);
    const int b = rid / SP, s = rid % SP;
    src = q + (((size_t)b * S_TOK + 1 + s) * DIM + kc * 8);
    dh = qph + ((size_t)rid * DIM + kc * 8);
    dl = qpl + ((size_t)rid * DIM + kc * 8);
  } else {
    const int cid = gid - QCH;  // < 24576
    src = cw + (size_t)cid * 8;
    dh = cwh + (size_t)cid * 8;
    dl = cwl + (size_t)cid * 8;
  }
  float4 v0 = *(const float4*)src;
  float4 v1 = *(const float4*)(src + 4);
  float v[8] = {v0.x, v0.y, v0.z, v0.w, v1.x, v1.y, v1.z, v1.w};
  bf16x8 h, l;
#pragma unroll
  for (int i = 0; i < 8; i++) {
    __bf16 hh = (__bf16)v[i];
    h[i] = hh;
    l[i] = (__bf16)(v[i] - (float)hh);
  }
  *(bf16x8*)dh = h;
  *(bf16x8*)dl = l;
}

// ---------------- Kernel A: qk[bl,c,s] = sum_d cw[c,d] * q[b,s+1,d] --------
// Pure-bf16 3-pass MFMA. Tile 64(c) x 144(s), BK=64 (128-B LDS rows),
// chunk-XOR swizzle slot = kc ^ (r&7): uniform banks on write AND read.
// Grid (4,4,bper) = 256 blocks/slice = exactly 1/CU.
__global__ __launch_bounds__(256) void qk_gemm_bf16(const __bf16* __restrict__ qph,
                                                    const __bf16* __restrict__ qpl,
                                                    const __bf16* __restrict__ cwh,
                                                    const __bf16* __restrict__ cwl,
                                                    float* __restrict__ qk, int b0) {
  const int bl = blockIdx.z;
  const int b = b0 + bl;
  const int s0 = blockIdx.x * 144;
  const int c0 = blockIdx.y * 64;
  __shared__ __align__(16) __bf16 sAH[64 * 64], sAL[64 * 64];
  __shared__ __align__(16) __bf16 sBH[144 * 64], sBL[144 * 64];

  const int tid = threadIdx.x;
  const int lane = tid & 63;
  const int wid = tid >> 6;      // wave = c-subtile
  const int wc = wid << 4;       // wave c-offset 0/16/32/48
  const int fr = lane & 15;
  const int kqm = lane >> 4;     // k-quarter 0..3
  const int frs = fr & 7;

  // staging coords
  const int rb = tid >> 3;   // 0..31
  const int kc = tid & 7;    // chunk in row
  const int slw = (kc ^ (rb & 7)) * 8;  // swizzled slot (bf16 elems)

  const __bf16* qbh = qph + (size_t)b * SP * DIM;
  const __bf16* qbl = qpl + (size_t)b * SP * DIM;

  f32x4 acc[9];
#pragma unroll
  for (int j = 0; j < 9; j++) acc[j] = (f32x4){0.f, 0.f, 0.f, 0.f};

  bf16x8 rAh[2], rAl[2], rBh[5], rBl[5];

#define LOADREGS(K0)                                                          \
  {                                                                           \
    const int k0_ = (K0);                                                     \
    _Pragma("unroll") for (int m = 0; m < 2; ++m) {                           \
      const size_t g = (size_t)(c0 + m * 32 + rb) * DIM + k0_ + kc * 8;       \
      rAh[m] = *(const bf16x8*)(cwh + g);                                     \
      rAl[m] = *(const bf16x8*)(cwl + g);                                     \
    }                                                                         \
    _Pragma("unroll") for (int m = 0; m < 4; ++m) {                           \
      const size_t g = (size_t)(s0 + m * 32 + rb) * DIM + k0_ + kc * 8;       \
      rBh[m] = *(const bf16x8*)(qbh + g);                                     \
      rBl[m] = *(const bf16x8*)(qbl + g);                                     \
    }                                                                         \
    if (tid < 128) {                                                          \
      const size_t g = (size_t)(s0 + 128 + rb) * DIM + k0_ + kc * 8;          \
      rBh[4] = *(const bf16x8*)(qbh + g);                                     \
      rBl[4] = *(const bf16x8*)(qbl + g);                                     \
    }                                                                         \
  }

  LOADREGS(0);
  for (int kt = 0; kt < 12; ++kt) {
    __syncthreads();  // previous iter's fragment readers done
#pragma unroll
    for (int m = 0; m < 2; ++m) {
      const int r = m * 32 + rb;
      *(bf16x8*)(sAH + r * 64 + slw) = rAh[m];
      *(bf16x8*)(sAL + r * 64 + slw) = rAl[m];
    }
#pragma unroll
    for (int m = 0; m < 4; ++m) {
      const int r = m * 32 + rb;
      *(bf16x8*)(sBH + r * 64 + slw) = rBh[m];
      *(bf16x8*)(sBL + r * 64 + slw) = rBl[m];
    }
    if (tid < 128) {
      const int r = 128 + rb;
      *(bf16x8*)(sBH + r * 64 + slw) = rBh[4];
      *(bf16x8*)(sBL + r * 64 + slw) = rBl[4];
    }
    __syncthreads();
    if (kt < 11) LOADREGS((kt + 1) * 64);  // prefetch hides under compute
#define MF(A, B, C) C = __builtin_amdgcn_mfma_f32_16x16x32_bf16(A, B, C, 0, 0, 0)
#pragma unroll
    for (int ks = 0; ks < 2; ++ks) {
      const int sl = ((ks * 4 + kqm) ^ frs) * 8;
      const bf16x8 ah = *(const bf16x8*)(sAH + (wc + fr) * 64 + sl);
      const bf16x8 al = *(const bf16x8*)(sAL + (wc + fr) * 64 + sl);
#pragma unroll
      for (int j = 0; j < 9; ++j) {
        const int br = j * 16 + fr;
        const bf16x8 bh = *(const bf16x8*)(sBH + br * 64 + sl);
        const bf16x8 bv = *(const bf16x8*)(sBL + br * 64 + sl);
        MF(ah, bh, acc[j]);
        MF(ah, bv, acc[j]);
        MF(al, bh, acc[j]);
      }
    }
#undef MF
  }
#undef LOADREGS
  // C/D layout (m89-verified): col(s) = lane&15, row(c) = (lane>>4)*4 + reg
  float* obase = qk + (size_t)bl * NC * SP;
#pragma unroll
  for (int j = 0; j < 9; ++j)
#pragma unroll
    for (int rr = 0; rr < 4; ++rr) {
      const int row = c0 + wc + kqm * 4 + rr;
      const int col = s0 + j * 16 + fr;
      obase[(size_t)row * SP + col] = acc[j][rr];
    }
}

// ---------------- Kernel B: top-16 + softmax -> atomic scatter into W ------
__global__ __launch_bounds__(256) void topk_scatter(const float* __restrict__ qk,
                                                    float* __restrict__ W, int b0) {
  const int lane = threadIdx.x & 63;
  const int wid = threadIdx.x >> 6;
  const int rcl = blockIdx.x * 4 + wid;  // slice-local (bl*NC + c)
  const int bl = rcl >> 8;
  const int b = b0 + bl;
  const float* rowp = qk + (size_t)rcl * SP;
  float v[9];
#pragma unroll
  for (int j = 0; j < 9; j++) v[j] = rowp[lane + 64 * j];

  float vals[TK];
  int idxs[TK];
#pragma unroll
  for (int t = 0; t < TK; t++) {
    float bv = -1e30f;
    int bj = 0;
#pragma unroll
    for (int j = 0; j < 9; j++)
      if (v[j] > bv) { bv = v[j]; bj = j; }
    int bs = lane + 64 * bj;
#pragma unroll
    for (int off = 32; off >= 1; off >>= 1) {
      float ov = __shfl_xor(bv, off);
      int os = __shfl_xor(bs, off);
      if (ov > bv || (ov == bv && os < bs)) { bv = ov; bs = os; }
    }
    vals[t] = bv;
    idxs[t] = bs;
    const int clr_j = bs >> 6;
    const int clr_lane = bs & 63;
#pragma unroll
    for (int j = 0; j < 9; j++)
      if (j == clr_j && clr_lane == lane) v[j] = -1e30f;
  }
  float m = vals[0];
  float sum = 0.f;
#pragma unroll
  for (int t = 0; t < TK; t++) sum += expf(vals[t] - m);
  if (lane == 0) {
    const float inv = 1.f / (sum * (float)NC);
#pragma unroll
    for (int t = 0; t < TK; t++)
      atomicAdd(&W[b * SP + idxs[t]], expf(vals[t] - m) * inv);
  }
}

// ---------------- Kernel C: hpart[ch,b,d] = sum_{s in chunk} W*q ------------
__global__ __launch_bounds__(256) void h_partial(const float* __restrict__ q,
                                                 const float* __restrict__ W,
                                                 float* __restrict__ hpart) {
  const int b = blockIdx.y;
  const int ch = blockIdx.z;
  const int d = blockIdx.x * 256 + threadIdx.x;
  __shared__ float Ws[HCHS];
  if (threadIdx.x < HCHS) Ws[threadIdx.x] = W[b * SP + ch * HCHS + threadIdx.x];
  __syncthreads();
  const float* qb = q + ((size_t)b * S_TOK + 1 + ch * HCHS) * DIM + d;
  float acc = 0.f;
#pragma unroll 8
  for (int s = 0; s < HCHS; s++) acc = fmaf(Ws[s], qb[(size_t)s * DIM], acc);
  hpart[((size_t)ch * NB + b) * DIM + d] = acc;
}

// ---------------- Kernel D: y = relu(sum_ch hpart) @ cls_w^T + cls_b --------
__global__ __launch_bounds__(256) void cls_head(const float* __restrict__ hp,
                                                const float* __restrict__ cw,
                                                const float* __restrict__ cb,
                                                float* __restrict__ y) {
  __shared__ float hs[NB * DIM];
  for (int i = threadIdx.x; i < NB * DIM; i += 256) {
    float s = 0.f;
#pragma unroll
    for (int ch = 0; ch < HCH; ch++) s += hp[(size_t)ch * NB * DIM + i];
    hs[i] = fmaxf(s, 0.f);
  }
  __syncthreads();
  const int lane = threadIdx.x & 63;
  const int n = blockIdx.x * 4 + (threadIdx.x >> 6);
  float wr[12];
#pragma unroll
  for (int j = 0; j < 12; j++) wr[j] = cw[(size_t)n * DIM + lane + 64 * j];
  const float bias = cb[n];
  for (int bb = 0; bb < NB; bb++) {
    float dot = 0.f;
#pragma unroll
    for (int j = 0; j < 12; j++)
      dot = fmaf(wr[j], hs[bb * DIM + lane + 64 * j], dot);
#pragma unroll
    for (int off = 32; off >= 1; off >>= 1) dot += __shfl_xor(dot, off);
    if (lane == 0) y[bb * NCLS + n] = dot + bias;
  }
}

extern "C" void kernel_launch(void* const* d_in, const int* in_sizes, int n_in,
                              void* d_out, int out_size, void* d_ws, size_t ws_size,
                              hipStream_t stream) {
  const float* q = (const float*)d_in[0];
  const float* cw = (const float*)d_in[1];
  const float* clsw = (const float*)d_in[2];
  const float* clsb = (const float*)d_in[3];
  float* out = (float*)d_out;

  __bf16* qph = (__bf16*)d_ws;                       // NB*SP*DIM bf16
  __bf16* qpl = qph + (size_t)NB * SP * DIM;
  __bf16* cwh = qpl + (size_t)NB * SP * DIM;         // NC*DIM
  __bf16* cwl = cwh + (size_t)NC * DIM;
  float* W = (float*)(cwl + (size_t)NC * DIM);       // NB*SP
  float* hpart = W + (size_t)NB * SP;                // HCH*NB*DIM
  float* qk = hpart + (size_t)HCH * NB * DIM;        // slice buffer
  const size_t aux_bytes = (size_t)((char*)qk - (char*)d_ws);

  int bper = NB;
  while (bper > 1 &&
         aux_bytes + (size_t)bper * NC * SP * sizeof(float) > ws_size)
    bper >>= 1;

  const int CVT_BLOCKS = (NB * SP * (DIM / 8) + NC * (DIM / 8)) / 256;  // 3552
  cvt_split_k<<<CVT_BLOCKS, 256, 0, stream>>>(q, cw, qph, qpl, cwh, cwl, W);

  for (int b0 = 0; b0 < NB; b0 += bper) {
    qk_gemm_bf16<<<dim3(4, 4, bper), 256, 0, stream>>>(qph, qpl, cwh, cwl, qk, b0);
    topk_scatter<<<(bper * NC) / 4, 256, 0, stream>>>(qk, W, b0);
  }
  h_partial<<<dim3(3, NB, HCH), 256, 0, stream>>>(q, W, hpart);
  cls_head<<<NCLS / 4, 256, 0, stream>>>(hpart, clsw, clsb, out);
}